// Round 3
// baseline (166.346 us; speedup 1.0000x reference)
//
#include <hip/hip_runtime.h>

#define NX   192
#define TW   8                 // output w-rows per block
#define HC   6                 // output h-slabs per block
#define NTH  384               // 8 w-rows x 48 d-groups
#define RS   200               // LDS row stride (floats): idx3 & idx196 are zero slots, data at 4..195
#define ROWS (TW + 2)          // 10 staged w-rows (halo)
#define LDSZ (ROWS * RS)       // 2000 floats per array per buffer
#define NVEC (ROWS * 48 * 2)   // 960 float4 loads per slab (pred+targ)
#define GW_  (NX / TW)         // 24
#define GH_  (NX / HC)         // 32
#define NBLK (GW_ * GH_)       // 768

static __device__ __forceinline__ float fast_rcp(float x) {
#if __has_builtin(__builtin_amdgcn_rcpf)
    return __builtin_amdgcn_rcpf(x);
#else
    return 1.f / x;
#endif
}

// Block: stages (TW+2) w-rows x 192 d of one h-slab into LDS (separate I/J arrays,
// aligned float4 in and out), double-buffered, one barrier per slab. Each thread
// computes 4 consecutive d outputs for one w-row: vertical (w) sums first, then
// sliding d-window, then a 2-deep h ring for the 3x3x3 sums -> NCC.
__global__ __launch_bounds__(NTH, 3)
void lncc_main(const float* __restrict__ pred, const float* __restrict__ targ,
               double* __restrict__ partial) {
    __shared__ __align__(16) float sI[2][LDSZ];
    __shared__ __align__(16) float sJ[2][LDSZ];
    __shared__ float wred[NTH / 64];

    const int tid = threadIdx.x;
    const int w0 = blockIdx.x * TW;
    const int h0 = blockIdx.y * HC;

    const int wi = tid / 48;        // 0..7  output w-row within tile
    const int k  = tid % 48;        // d-group
    const int d0 = 4 * k;           // first output d (0..188), 16B-aligned in LDS

    // staging descriptors: 3 batches of NTH float4 loads cover NVEC=960
    bool sOK[3], sHAS[3], sJA[3];
    int  sDST[3], sOFF[3];
#pragma unroll
    for (int t = 0; t < 3; ++t) {
        const int i = tid + NTH * t;
        const bool inb = (i < NVEC);
        const int a = (i >= NVEC / 2) ? 1 : 0;
        const int j = inb ? (i - a * (NVEC / 2)) : 0;
        const int row = j / 48;            // 0..9
        const int c4  = j - row * 48;      // quad within row
        const int gw  = w0 - 1 + row;
        sHAS[t] = inb;
        sJA[t]  = (a != 0);
        sDST[t] = row * RS + 4 + 4 * c4;
        sOK[t]  = inb && ((unsigned)gw < NX);
        sOFF[t] = gw * NX + 4 * c4;        // + h*NX*NX at load time
    }

    // zero the d-halo slots (idx 3 and 196) of every row, both arrays, both buffers
    if (tid < 80) {
        const int side = tid & 1;
        const int q = tid >> 1;            // 0..39
        const int buf = q / 20;
        const int arr = (q / 10) % 2;
        const int row = q % 10;
        float* base = arr ? sJ[buf] : sI[buf];
        base[row * RS + (side ? 196 : 3)] = 0.f;
    }

    float4 pf[3];
    auto prefetch = [&](int h) {
        const bool hin = ((unsigned)h < NX);
        const int hb = h * NX * NX;
#pragma unroll
        for (int t = 0; t < 3; ++t) {
            float4 v = make_float4(0.f, 0.f, 0.f, 0.f);
            if (hin && sOK[t]) {
                const float* s = sJA[t] ? targ : pred;
                v = *(const float4*)(s + hb + sOFF[t]);
            }
            pf[t] = v;
        }
    };

    prefetch(h0 - 1);                       // slab for s = 0

    float ring[2][5][4];
    float acc = 0.f;
    const float inv = 1.f / 27.f;

#pragma unroll
    for (int s = 0; s < HC + 2; ++s) {
        const int b = s & 1;
        // stash the prefetched slab (h = h0-1+s) into LDS buffer b
#pragma unroll
        for (int t = 0; t < 3; ++t) {
            if (sHAS[t]) {
                float* dst = (sJA[t] ? sJ[b] : sI[b]) + sDST[t];
                *(float4*)dst = pf[t];
            }
        }
        __syncthreads();
        if (s <= HC) prefetch(h0 + s);      // slab for next iteration

        // vertical (w) sums over rows wi..wi+2, d columns j=0..5 (d = d0-1+j)
        float vI[6], vJ[6], vII[6], vJJ[6], vIJ[6];
#pragma unroll
        for (int j = 0; j < 6; ++j) vI[j] = vJ[j] = vII[j] = vJJ[j] = vIJ[j] = 0.f;
#pragma unroll
        for (int r = 0; r < 3; ++r) {
            const float* pI = &sI[b][(wi + r) * RS + d0];
            const float* pJ = &sJ[b][(wi + r) * RS + d0];
            float fI[12], fJ[12];
            *(float4*)&fI[0] = *(const float4*)(pI + 0);
            *(float4*)&fI[4] = *(const float4*)(pI + 4);
            *(float4*)&fI[8] = *(const float4*)(pI + 8);
            *(float4*)&fJ[0] = *(const float4*)(pJ + 0);
            *(float4*)&fJ[4] = *(const float4*)(pJ + 4);
            *(float4*)&fJ[8] = *(const float4*)(pJ + 8);
#pragma unroll
            for (int j = 0; j < 6; ++j) {
                const float a = fI[3 + j];
                const float c = fJ[3 + j];
                vI[j] += a; vJ[j] += c;
                vII[j] = fmaf(a, a, vII[j]);
                vJJ[j] = fmaf(c, c, vJJ[j]);
                vIJ[j] = fmaf(a, c, vIJ[j]);
            }
        }

        // d-window sums -> this slab's 2D sums; 3-slab ring -> 3D sums -> NCC
#pragma unroll
        for (int o = 0; o < 4; ++o) {
            const float nI2  = vI[o]  + vI[o + 1]  + vI[o + 2];
            const float nJ2  = vJ[o]  + vJ[o + 1]  + vJ[o + 2];
            const float nII2 = vII[o] + vII[o + 1] + vII[o + 2];
            const float nJJ2 = vJJ[o] + vJJ[o + 1] + vJJ[o + 2];
            const float nIJ2 = vIJ[o] + vIJ[o + 1] + vIJ[o + 2];
            if (s >= 2) {                    // emit output at h = h0 + s - 2
                const float Is  = ring[s & 1][0][o] + ring[(s + 1) & 1][0][o] + nI2;
                const float Js  = ring[s & 1][1][o] + ring[(s + 1) & 1][1][o] + nJ2;
                const float IIs = ring[s & 1][2][o] + ring[(s + 1) & 1][2][o] + nII2;
                const float JJs = ring[s & 1][3][o] + ring[(s + 1) & 1][3][o] + nJJ2;
                const float IJs = ring[s & 1][4][o] + ring[(s + 1) & 1][4][o] + nIJ2;
                const float uI = Is * inv;
                const float uJ = Js * inv;
                const float cross = fmaf(-uJ, Is, IJs);
                const float Ivar  = fmaf(-uI, Is, IIs);
                const float Jvar  = fmaf(-uJ, Js, JJs);
                const float den   = fmaf(Ivar, Jvar, 1e-5f);
                acc = fmaf(cross * cross, fast_rcp(den), acc);
            }
            ring[s & 1][0][o] = nI2;
            ring[s & 1][1][o] = nJ2;
            ring[s & 1][2][o] = nII2;
            ring[s & 1][3][o] = nJJ2;
            ring[s & 1][4][o] = nIJ2;
        }
    }

    // block reduction -> one double partial per block
    float v = acc;
#pragma unroll
    for (int off = 32; off > 0; off >>= 1) v += __shfl_down(v, off);
    if ((tid & 63) == 0) wred[tid >> 6] = v;
    __syncthreads();
    if (tid == 0) {
        double t = 0.0;
#pragma unroll
        for (int i = 0; i < NTH / 64; ++i) t += (double)wred[i];
        partial[blockIdx.y * GW_ + blockIdx.x] = t;
    }
}

__global__ __launch_bounds__(256)
void lncc_reduce(const double* __restrict__ partial, float* __restrict__ out) {
    __shared__ double dred[4];
    double sum = 0.0;
    for (int i = threadIdx.x; i < NBLK; i += 256) sum += partial[i];
#pragma unroll
    for (int off = 32; off > 0; off >>= 1) sum += __shfl_down(sum, off);
    if ((threadIdx.x & 63) == 0) dred[threadIdx.x >> 6] = sum;
    __syncthreads();
    if (threadIdx.x == 0) {
        const double n = (double)NX * NX * NX;
        out[0] = (float)(-(dred[0] + dred[1] + dred[2] + dred[3]) / n);
    }
}

extern "C" void kernel_launch(void* const* d_in, const int* in_sizes, int n_in,
                              void* d_out, int out_size, void* d_ws, size_t ws_size,
                              hipStream_t stream) {
    const float* pred = (const float*)d_in[0];
    const float* targ = (const float*)d_in[1];
    double* partial = (double*)d_ws;      // NBLK doubles, fully overwritten each call
    float* out = (float*)d_out;

    dim3 grid(GW_, GH_);                  // 24 x 32 = 768 blocks
    lncc_main<<<grid, NTH, 0, stream>>>(pred, targ, partial);
    lncc_reduce<<<1, 256, 0, stream>>>(partial, out);
}

// Round 4
// 124.341 us; speedup vs baseline: 1.3378x; 1.3378x over previous
//
#include <hip/hip_runtime.h>

#define NX   192
#define NXY  (NX * NX)
#define XG   48              // x-groups per row (4 outputs each)
#define YB   8               // y rows per block
#define ZC   6               // z outputs per block
#define NTH  (XG * YB)       // 384 threads = 6 waves
#define GY   (NX / YB)       // 24
#define GZ   (NX / ZC)       // 32
#define NBLK (GY * GZ)       // 768

static __device__ __forceinline__ float frcp(float x) {
#if __has_builtin(__builtin_amdgcn_rcpf)
    return __builtin_amdgcn_rcpf(x);
#else
    return 1.f / x;
#endif
}

// x-window sums: col c = x0-1+c, cols 0..3 in v, cols 4,5 in s4,s5.
// output o needs cols o,o+1,o+2.
#define WIN(n, v, s4, s5)                    \
    n.x = v.x + v.y + v.z;                   \
    n.y = v.y + v.z + v.w;                   \
    n.z = v.z + v.w + s4;                    \
    n.w = v.w + s4 + s5;

#define NCCC(o)                                                            \
    {                                                                      \
        const float Is  = p0I.o  + p1I.o  + nI.o;                          \
        const float Js  = p0J.o  + p1J.o  + nJ.o;                          \
        const float IIs = p0II.o + p1II.o + nII.o;                         \
        const float JJs = p0JJ.o + p1JJ.o + nJJ.o;                         \
        const float IJs = p0IJ.o + p1IJ.o + nIJ.o;                         \
        const float uI = Is * inv27;                                       \
        const float uJ = Js * inv27;                                       \
        const float cross = fmaf(-uJ, Is, IJs);                            \
        const float Iv    = fmaf(-uI, Is, IIs);                            \
        const float Jv    = fmaf(-uJ, Js, JJs);                            \
        const float den   = fmaf(Iv, Jv, 1e-5f);                           \
        acc.o = fmaf(cross * cross, frcp(den), acc.o);                     \
    }

// Register-only LNCC: no LDS staging, no barriers. Each thread owns 4
// consecutive x outputs at one y, sliding over a ZC-deep z-chunk. Per slice:
// 3 y-rows x (float4 + 2 edge scalars) x 2 arrays from global (L1-cached,
// 3x y-redundancy absorbed by L1), column stats in NAMED float4/scalar
// registers (no address-taken arrays -> no scratch), 2-deep named-float4
// z-ring, NCC per component. Latency hidden purely by TLP (18 waves/CU).
__global__ __launch_bounds__(NTH)
void lncc_main(const float* __restrict__ pred, const float* __restrict__ targ,
               double* __restrict__ partial) {
    __shared__ float wred[NTH / 64];

    const int k  = threadIdx.x;            // 0..47
    const int x0 = 4 * k;
    const int y  = blockIdx.y * YB + threadIdx.y;
    const int z0 = blockIdx.z * ZC;
    const bool okxm = (k > 0);
    const bool okxp = (k < XG - 1);
    const float inv27 = 1.f / 27.f;

    float4 zero4 = make_float4(0.f, 0.f, 0.f, 0.f);
    float4 p0I = zero4, p0J = zero4, p0II = zero4, p0JJ = zero4, p0IJ = zero4;
    float4 p1I = zero4, p1J = zero4, p1II = zero4, p1JJ = zero4, p1IJ = zero4;
    float4 acc = zero4;

    for (int s = 0; s < ZC + 2; ++s) {
        const int z = z0 - 1 + s;

        // ---- column stats for this slice: cols x0-1 .. x0+4 ----
        float4 vI = zero4, vJ = zero4, vII = zero4, vJJ = zero4, vIJ = zero4;
        float vI4 = 0.f, vI5 = 0.f, vJ4 = 0.f, vJ5 = 0.f;
        float vII4 = 0.f, vII5 = 0.f, vJJ4 = 0.f, vJJ5 = 0.f;
        float vIJ4 = 0.f, vIJ5 = 0.f;

        if ((unsigned)z < NX) {                       // wave-uniform
            const float* pz = pred + (size_t)z * NXY;
            const float* tz = targ + (size_t)z * NXY;
#pragma unroll
            for (int ry = 0; ry < 3; ++ry) {
                const int yy = y - 1 + ry;
                float4 qa = zero4, qb = zero4;
                float ea0 = 0.f, ea5 = 0.f, eb0 = 0.f, eb5 = 0.f;
                if ((unsigned)yy < NX) {
                    const float* ra = pz + yy * NX + x0;
                    const float* rb = tz + yy * NX + x0;
                    qa = *(const float4*)ra;
                    qb = *(const float4*)rb;
                    if (okxm) { ea0 = ra[-1]; eb0 = rb[-1]; }
                    if (okxp) { ea5 = ra[4];  eb5 = rb[4]; }
                }
                const float4 ra4 = make_float4(ea0, qa.x, qa.y, qa.z);
                const float4 rb4 = make_float4(eb0, qb.x, qb.y, qb.z);
                vI.x += ra4.x; vI.y += ra4.y; vI.z += ra4.z; vI.w += ra4.w;
                vJ.x += rb4.x; vJ.y += rb4.y; vJ.z += rb4.z; vJ.w += rb4.w;
                vII.x = fmaf(ra4.x, ra4.x, vII.x); vII.y = fmaf(ra4.y, ra4.y, vII.y);
                vII.z = fmaf(ra4.z, ra4.z, vII.z); vII.w = fmaf(ra4.w, ra4.w, vII.w);
                vJJ.x = fmaf(rb4.x, rb4.x, vJJ.x); vJJ.y = fmaf(rb4.y, rb4.y, vJJ.y);
                vJJ.z = fmaf(rb4.z, rb4.z, vJJ.z); vJJ.w = fmaf(rb4.w, rb4.w, vJJ.w);
                vIJ.x = fmaf(ra4.x, rb4.x, vIJ.x); vIJ.y = fmaf(ra4.y, rb4.y, vIJ.y);
                vIJ.z = fmaf(ra4.z, rb4.z, vIJ.z); vIJ.w = fmaf(ra4.w, rb4.w, vIJ.w);
                vI4 += qa.w;  vI5 += ea5;
                vJ4 += qb.w;  vJ5 += eb5;
                vII4 = fmaf(qa.w, qa.w, vII4);  vII5 = fmaf(ea5, ea5, vII5);
                vJJ4 = fmaf(qb.w, qb.w, vJJ4);  vJJ5 = fmaf(eb5, eb5, vJJ5);
                vIJ4 = fmaf(qa.w, qb.w, vIJ4);  vIJ5 = fmaf(ea5, eb5, vIJ5);
            }
        }

        // ---- x-window sums -> this slice's 2D sums (4 outputs) ----
        float4 nI, nJ, nII, nJJ, nIJ;
        WIN(nI,  vI,  vI4,  vI5)
        WIN(nJ,  vJ,  vJ4,  vJ5)
        WIN(nII, vII, vII4, vII5)
        WIN(nJJ, vJJ, vJJ4, vJJ5)
        WIN(nIJ, vIJ, vIJ4, vIJ5)

        // ---- emit output z-1 once ring holds z-2,z-1,z ----
        if (s >= 2) {
            NCCC(x) NCCC(y) NCCC(z) NCCC(w)
        }
        p0I = p1I; p0J = p1J; p0II = p1II; p0JJ = p1JJ; p0IJ = p1IJ;
        p1I = nI;  p1J = nJ;  p1II = nII;  p1JJ = nJJ;  p1IJ = nIJ;
    }

    // ---- block reduction -> one double partial per block ----
    float v = acc.x + acc.y + acc.z + acc.w;
#pragma unroll
    for (int off = 32; off > 0; off >>= 1) v += __shfl_down(v, off);
    const int tid = threadIdx.y * XG + threadIdx.x;
    if ((tid & 63) == 0) wred[tid >> 6] = v;
    __syncthreads();
    if (tid == 0) {
        double t = 0.0;
#pragma unroll
        for (int i = 0; i < NTH / 64; ++i) t += (double)wred[i];
        partial[blockIdx.z * GY + blockIdx.y] = t;
    }
}

__global__ __launch_bounds__(256)
void lncc_reduce(const double* __restrict__ partial, float* __restrict__ out) {
    __shared__ double dred[4];
    double sum = 0.0;
    for (int i = threadIdx.x; i < NBLK; i += 256) sum += partial[i];
#pragma unroll
    for (int off = 32; off > 0; off >>= 1) sum += __shfl_down(sum, off);
    if ((threadIdx.x & 63) == 0) dred[threadIdx.x >> 6] = sum;
    __syncthreads();
    if (threadIdx.x == 0) {
        const double n = (double)NX * NX * NX;
        out[0] = (float)(-(dred[0] + dred[1] + dred[2] + dred[3]) / n);
    }
}

extern "C" void kernel_launch(void* const* d_in, const int* in_sizes, int n_in,
                              void* d_out, int out_size, void* d_ws, size_t ws_size,
                              hipStream_t stream) {
    const float* pred = (const float*)d_in[0];
    const float* targ = (const float*)d_in[1];
    double* partial = (double*)d_ws;
    float* out = (float*)d_out;

    dim3 grid(1, GY, GZ);                 // 1 x 24 x 32 = 768 blocks
    dim3 block(XG, YB);                   // 48 x 8 = 384 threads
    lncc_main<<<grid, block, 0, stream>>>(pred, targ, partial);
    lncc_reduce<<<1, 256, 0, stream>>>(partial, out);
}